// Round 4
// baseline (467.050 us; speedup 1.0000x reference)
//
#include <hip/hip_runtime.h>
#include <hip/hip_bf16.h>

static constexpr int KDIM = 96;
static constexpr int BSH = 7;              // 128 nodes per bucket
static constexpr int BNODES = 1 << BSH;
static constexpr int MAXBK = 400;          // >= ceil(50000/128)=391
static constexpr int NSLICE = 6;           // 6 x 16-float feature slices

// ---- bucketed CSR build ----------------------------------------------------

__global__ void kb_hist(const int* __restrict__ dst, int* __restrict__ gbcnt,
                        int E, int NBK) {
  __shared__ int h[MAXBK];
  for (int i = threadIdx.x; i < NBK; i += blockDim.x) h[i] = 0;
  __syncthreads();
  for (int e = blockIdx.x * blockDim.x + threadIdx.x; e < E; e += gridDim.x * blockDim.x)
    atomicAdd(&h[dst[e] >> BSH], 1);
  __syncthreads();
  for (int i = threadIdx.x; i < NBK; i += blockDim.x)
    if (h[i]) atomicAdd(&gbcnt[i], h[i]);
}

__global__ void kb_scanb(const int* __restrict__ gbcnt, int* __restrict__ bstart,
                         int* __restrict__ bcur, int NBK) {
  __shared__ int s[512];
  int t = threadIdx.x;
  int v = (t < NBK) ? gbcnt[t] : 0;
  s[t] = v;
  __syncthreads();
  for (int o = 1; o < 512; o <<= 1) {
    int a = (t >= o) ? s[t - o] : 0;
    __syncthreads();
    s[t] += a;
    __syncthreads();
  }
  if (t < NBK) {
    int excl = s[t] - v;
    bstart[t] = excl;
    bcur[t] = excl;
  }
  if (t == 511) bstart[NBK] = s[511];
}

__global__ __launch_bounds__(256) void kb_scatter(const int* __restrict__ src,
                                                  const int* __restrict__ dst,
                                                  int* __restrict__ bcur,
                                                  int2* __restrict__ tmp,
                                                  int E, int NBK, int chunk) {
  __shared__ int h[MAXBK];
  __shared__ int base[MAXBK];
  int lo = blockIdx.x * chunk;
  int hi = min(lo + chunk, E);
  for (int i = threadIdx.x; i < NBK; i += 256) h[i] = 0;
  __syncthreads();
  for (int e = lo + threadIdx.x; e < hi; e += 256) atomicAdd(&h[dst[e] >> BSH], 1);
  __syncthreads();
  for (int i = threadIdx.x; i < NBK; i += 256) {
    int c = h[i];
    base[i] = c ? atomicAdd(&bcur[i], c) : 0;
    h[i] = 0;
  }
  __syncthreads();
  for (int e = lo + threadIdx.x; e < hi; e += 256) {
    int d = dst[e];
    int b = d >> BSH;
    int p = base[b] + atomicAdd(&h[b], 1);
    tmp[p] = make_int2(src[e], d);
  }
}

__global__ __launch_bounds__(256) void kb_cnt(const int2* __restrict__ tmp,
                                              const int* __restrict__ bstart,
                                              int* __restrict__ cnt,
                                              float* __restrict__ dinv, int N) {
  __shared__ int h[BNODES];
  int b = blockIdx.x;
  for (int i = threadIdx.x; i < BNODES; i += 256) h[i] = 0;
  __syncthreads();
  int lo = bstart[b], hi = bstart[b + 1];
  for (int p = lo + threadIdx.x; p < hi; p += 256)
    atomicAdd(&h[tmp[p].y & (BNODES - 1)], 1);
  __syncthreads();
  int v0 = b << BSH;
  for (int i = threadIdx.x; i < BNODES; i += 256) {
    int v = v0 + i;
    if (v < N) {
      int c = h[i];
      cnt[v] = c;
      dinv[v] = rsqrtf((float)c + 1.0f);  // +1 self-loop
    }
  }
}

// scans over PADDED counts (rows padded to multiple of 4 edges)
__global__ void k_scan1(const int* __restrict__ cnt, int* __restrict__ rowstart,
                        int* __restrict__ bsum, int N) {
  __shared__ int s[256];
  int t = threadIdx.x;
  int i = blockIdx.x * 256 + t;
  s[t] = (i < N) ? ((cnt[i] + 3) & ~3) : 0;
  __syncthreads();
  for (int o = 1; o < 256; o <<= 1) {
    int add = (t >= o) ? s[t - o] : 0;
    __syncthreads();
    s[t] += add;
    __syncthreads();
  }
  if (i < N) rowstart[i + 1] = s[t];
  if (t == 255) bsum[blockIdx.x] = s[255];
}

__global__ void k_scan2(int* __restrict__ bsum, int NB) {
  __shared__ int s[1024];
  int t = threadIdx.x;
  s[t] = (t < NB) ? bsum[t] : 0;
  __syncthreads();
  for (int o = 1; o < 1024; o <<= 1) {
    int add = (t >= o) ? s[t - o] : 0;
    __syncthreads();
    s[t] += add;
    __syncthreads();
  }
  if (t < NB) bsum[t] = s[t];
}

__global__ void k_scan3(int* __restrict__ rowstart, const int* __restrict__ bsum, int N) {
  int i = blockIdx.x * blockDim.x + threadIdx.x;
  if (i == 0) rowstart[0] = 0;
  if (i < N && blockIdx.x > 0) rowstart[i + 1] += bsum[blockIdx.x - 1];
}

__global__ __launch_bounds__(256) void kb_final(const int2* __restrict__ tmp,
                                                const int* __restrict__ bstart,
                                                const int* __restrict__ rowstart,
                                                const float* __restrict__ dinv,
                                                int2* __restrict__ ew, int N) {
  __shared__ int prow[BNODES];
  __shared__ int lcur[BNODES];
  int b = blockIdx.x;
  int v0 = b << BSH;
  for (int i = threadIdx.x; i < BNODES; i += 256) {
    int v = v0 + i;
    prow[i] = (v < N) ? rowstart[v] : 0;
    lcur[i] = 0;
  }
  __syncthreads();
  int lo = bstart[b], hi = bstart[b + 1];
  for (int p = lo + threadIdx.x; p < hi; p += 256) {
    int2 sd = tmp[p];
    int dl = sd.y & (BNODES - 1);
    int pos = prow[dl] + atomicAdd(&lcur[dl], 1);
    ew[pos] = make_int2(sd.x, __float_as_int(dinv[sd.x]));
  }
  __syncthreads();
  for (int i = threadIdx.x; i < BNODES; i += 256) {
    int v = v0 + i;
    if (v < N) {
      int c = lcur[i];
      int p = prow[i] + c;
      int end = prow[i] + ((c + 3) & ~3);
      for (; p < end; ++p) ew[p] = make_int2(0, 0);  // w=0: contributes nothing
    }
  }
}

// ---- dense transform -------------------------------------------------------
// SLICED=true writes slice-major [6][N][16] for the feature-sliced aggregation.

template <int DOUT, bool SLICED>
__global__ __launch_bounds__(256) void k_gemm(const float* __restrict__ x,
                                              const float* __restrict__ Wg,
                                              float* __restrict__ out, int N) {
  __shared__ __align__(16) float Wl[KDIM * DOUT];
  __shared__ __align__(16) float xl[64 * 97];
  int tid = threadIdx.x;
  for (int i = tid; i < KDIM * DOUT; i += 256) Wl[i] = Wg[i];
  int base = blockIdx.x * 64;
  for (int i = tid; i < 64 * KDIM; i += 256) {
    int n = i / KDIM, k = i - n * KDIM;
    int gn = base + n;
    xl[n * 97 + k] = (gn < N) ? x[(size_t)gn * KDIM + k] : 0.f;
  }
  __syncthreads();
  const int tl = tid & 7;
  const int tn = tid >> 3;
  constexpr int M = DOUT / 32;
  float4 accA[M], accB[M];
#pragma unroll
  for (int m = 0; m < M; ++m) {
    accA[m] = float4{0.f, 0.f, 0.f, 0.f};
    accB[m] = float4{0.f, 0.f, 0.f, 0.f};
  }
  const float4* W4 = (const float4*)Wl;
#pragma unroll 4
  for (int k = 0; k < KDIM; ++k) {
    float xa = xl[tn * 97 + k];
    float xb = xl[(tn + 32) * 97 + k];
#pragma unroll
    for (int m = 0; m < M; ++m) {
      float4 ww = W4[k * (DOUT / 4) + tl + 8 * m];
      accA[m].x = fmaf(xa, ww.x, accA[m].x);
      accA[m].y = fmaf(xa, ww.y, accA[m].y);
      accA[m].z = fmaf(xa, ww.z, accA[m].z);
      accA[m].w = fmaf(xa, ww.w, accA[m].w);
      accB[m].x = fmaf(xb, ww.x, accB[m].x);
      accB[m].y = fmaf(xb, ww.y, accB[m].y);
      accB[m].z = fmaf(xb, ww.z, accB[m].z);
      accB[m].w = fmaf(xb, ww.w, accB[m].w);
    }
  }
  int nA = base + tn, nB = base + tn + 32;
#pragma unroll
  for (int m = 0; m < M; ++m) {
    int j0 = 4 * (tl + 8 * m);
    if (SLICED) {
      size_t sbase = (size_t)(j0 >> 4) * N * 16 + (j0 & 15);
      if (nA < N) *(float4*)(out + sbase + (size_t)nA * 16) = accA[m];
      if (nB < N) *(float4*)(out + sbase + (size_t)nB * 16) = accB[m];
    } else {
      if (nA < N) *(float4*)(out + (size_t)nA * DOUT + j0) = accA[m];
      if (nB < N) *(float4*)(out + (size_t)nB * DOUT + j0) = accB[m];
    }
  }
}

// ---- feature-sliced aggregation --------------------------------------------
// t: [6][N][16] slice-major. slot = blockIdx.x & 7 -> XCD pin; slots 0..5 each
// handle one 3.2MB slice (fits 4MB per-XCD L2); gathers = single 64B lines.
// Wave per node: 4 edge-groups x 16 feature lanes; cross-group shfl reduce.
// out: row-major [N][96].

template <bool RELU>
__global__ __launch_bounds__(256) void k_aggF(const float* __restrict__ t,
                                              const int* __restrict__ rowstart,
                                              const int2* __restrict__ ew,
                                              const float* __restrict__ dinv,
                                              const float* __restrict__ bias,
                                              float* __restrict__ out, int N) {
  int slot = blockIdx.x & 7;
  if (slot >= NSLICE) return;                 // XCDs 6,7 idle: L2 BW is the binding resource
  int item = blockIdx.x >> 3;
  int wv = threadIdx.x >> 6;
  int v = item * 4 + wv;
  if (v >= N) return;
  int lane = threadIdx.x & 63;
  int g = lane >> 4;                          // edge group 0..3
  int f = lane & 15;                          // feature within slice
  const float* ts = t + (size_t)slot * N * 16;
  float dv = dinv[v];
  float acc = (g == 0) ? dv * ts[(size_t)v * 16 + f] : 0.f;  // self-loop in group 0
  int e = rowstart[v];
  const int e1 = rowstart[v + 1];             // padded to x4
  for (; e + 8 <= e1; e += 8) {               // 2 independent 4-edge chains
    int2 ma = ew[e + g];
    int2 mb = ew[e + 4 + g];
    float va = ts[(size_t)ma.x * 16 + f];
    float vb = ts[(size_t)mb.x * 16 + f];
    acc = fmaf(__int_as_float(ma.y), va, acc);
    acc = fmaf(__int_as_float(mb.y), vb, acc);
  }
  if (e < e1) {
    int2 m = ew[e + g];
    acc = fmaf(__int_as_float(m.y), ts[(size_t)m.x * 16 + f], acc);
  }
  acc += __shfl_xor(acc, 16);
  acc += __shfl_xor(acc, 32);
  if (lane < 16) {
    float r = fmaf(dv, acc, bias[slot * 16 + f]);
    if (RELU) r = fmaxf(r, 0.f);
    out[(size_t)v * 96 + slot * 16 + f] = r;
  }
}

// D=32 final aggregation (row-major t), half-wave per node, pad-4 CSR.
__global__ __launch_bounds__(256) void k_agg32(const float* __restrict__ t,
                                               const int* __restrict__ rowstart,
                                               const int2* __restrict__ ew,
                                               const float* __restrict__ dinv,
                                               const float* __restrict__ bias,
                                               float* __restrict__ out, int N) {
  int half = threadIdx.x >> 5;
  int lane = threadIdx.x & 31;
  int v = blockIdx.x * 8 + half;
  if (v >= N) return;
  float dv = dinv[v];
  float acc = dv * t[(size_t)v * 32 + lane];
  int e = rowstart[v];
  const int e1 = rowstart[v + 1];
  for (; e + 8 <= e1; e += 8) {
    const int4* m4 = (const int4*)(ew + e);
    int4 q0 = m4[0], q1 = m4[1], q2 = m4[2], q3 = m4[3];
    float a0 = t[(size_t)q0.x * 32 + lane];
    float a1 = t[(size_t)q0.z * 32 + lane];
    float a2 = t[(size_t)q1.x * 32 + lane];
    float a3 = t[(size_t)q1.z * 32 + lane];
    float a4 = t[(size_t)q2.x * 32 + lane];
    float a5 = t[(size_t)q2.z * 32 + lane];
    float a6 = t[(size_t)q3.x * 32 + lane];
    float a7 = t[(size_t)q3.z * 32 + lane];
    acc = fmaf(__int_as_float(q0.y), a0, acc);
    acc = fmaf(__int_as_float(q0.w), a1, acc);
    acc = fmaf(__int_as_float(q1.y), a2, acc);
    acc = fmaf(__int_as_float(q1.w), a3, acc);
    acc = fmaf(__int_as_float(q2.y), a4, acc);
    acc = fmaf(__int_as_float(q2.w), a5, acc);
    acc = fmaf(__int_as_float(q3.y), a6, acc);
    acc = fmaf(__int_as_float(q3.w), a7, acc);
  }
  if (e < e1) {  // exactly 4 remaining (pad-4)
    const int4* m4 = (const int4*)(ew + e);
    int4 q0 = m4[0], q1 = m4[1];
    float a0 = t[(size_t)q0.x * 32 + lane];
    float a1 = t[(size_t)q0.z * 32 + lane];
    float a2 = t[(size_t)q1.x * 32 + lane];
    float a3 = t[(size_t)q1.z * 32 + lane];
    acc = fmaf(__int_as_float(q0.y), a0, acc);
    acc = fmaf(__int_as_float(q0.w), a1, acc);
    acc = fmaf(__int_as_float(q1.y), a2, acc);
    acc = fmaf(__int_as_float(q1.w), a3, acc);
  }
  out[(size_t)v * 32 + lane] = fmaf(dv, acc, bias[lane]);
}

// ---- launch ----------------------------------------------------------------

extern "C" void kernel_launch(void* const* d_in, const int* in_sizes, int n_in,
                              void* d_out, int out_size, void* d_ws, size_t ws_size,
                              hipStream_t stream) {
  const float* x  = (const float*)d_in[0];
  const int*   ei = (const int*)d_in[1];
  const float* W1 = (const float*)d_in[2];
  const float* b1 = (const float*)d_in[3];
  const float* W2 = (const float*)d_in[4];
  const float* b2 = (const float*)d_in[5];
  const float* W3 = (const float*)d_in[6];
  const float* b3 = (const float*)d_in[7];
  float* out = (float*)d_out;

  const int N = in_sizes[0] / KDIM;
  const int E = in_sizes[1] / 2;
  const int* src = ei;
  const int* dst = ei + E;
  const int NBK = (N + BNODES - 1) >> BSH;

  char* w = (char*)d_ws;
  size_t off = 0;
  auto alloc = [&](size_t bytes) {
    char* p = w + off;
    off = (off + bytes + 255) & ~(size_t)255;
    return p;
  };
  int*   gbcnt    = (int*)alloc((size_t)MAXBK * 4);
  int*   bstart   = (int*)alloc((size_t)(MAXBK + 1) * 4);
  int*   bcur     = (int*)alloc((size_t)MAXBK * 4);
  int*   cnt      = (int*)alloc((size_t)N * 4);
  float* dinv     = (float*)alloc((size_t)N * 4);
  int*   rowstart = (int*)alloc((size_t)(N + 1) * 4);
  int*   bsum     = (int*)alloc(4096);
  int2*  tmp      = (int2*)alloc((size_t)E * 8);
  int2*  ew       = (int2*)alloc((size_t)(E + 4 * (size_t)N) * 8);  // pad-4 CSR
  float* tbuf     = (float*)alloc((size_t)N * KDIM * 4);
  float* hbuf     = (float*)alloc((size_t)N * KDIM * 4);

  hipMemsetAsync(gbcnt, 0, (size_t)NBK * 4, stream);

  const int gN = (N + 255) / 256;
  const int NCH = 512;
  const int chunk = (E + NCH - 1) / NCH;

  kb_hist<<<256, 256, 0, stream>>>(dst, gbcnt, E, NBK);
  kb_scanb<<<1, 512, 0, stream>>>(gbcnt, bstart, bcur, NBK);
  kb_scatter<<<NCH, 256, 0, stream>>>(src, dst, bcur, tmp, E, NBK, chunk);
  kb_cnt<<<NBK, 256, 0, stream>>>(tmp, bstart, cnt, dinv, N);
  k_scan1<<<gN, 256, 0, stream>>>(cnt, rowstart, bsum, N);
  k_scan2<<<1, 1024, 0, stream>>>(bsum, gN);
  k_scan3<<<gN, 256, 0, stream>>>(rowstart, bsum, N);
  kb_final<<<NBK, 256, 0, stream>>>(tmp, bstart, rowstart, dinv, ew, N);

  const int gG = (N + 63) / 64;
  const int gA = ((N + 3) / 4) * 8;  // 8 slots: 6 feature slices + 2 idle XCDs
  k_gemm<96, true><<<gG, 256, 0, stream>>>(x, W1, tbuf, N);
  k_aggF<true><<<gA, 256, 0, stream>>>(tbuf, rowstart, ew, dinv, b1, hbuf, N);
  k_gemm<96, true><<<gG, 256, 0, stream>>>(hbuf, W2, tbuf, N);
  k_aggF<true><<<gA, 256, 0, stream>>>(tbuf, rowstart, ew, dinv, b2, hbuf, N);
  k_gemm<32, false><<<gG, 256, 0, stream>>>(hbuf, W3, tbuf, N);
  k_agg32<<<(N + 7) / 8, 256, 0, stream>>>(tbuf, rowstart, ew, dinv, b3, out, N);
}